// Round 8
// baseline (229.261 us; speedup 1.0000x reference)
//
#include <hip/hip_runtime.h>

typedef float f32x2 __attribute__((ext_vector_type(2)));

#define BB 16
#define FF 256
#define TT 8192
#define F_CHUNK 8
#define ROWS (F_CHUNK + 2)
#define THREADS 256
#define TBLK 512             // floats per block along t
#define NXBLK (TT / TBLK)    // 16 t-blocks
#define LROW 512             // 2KB LDS row; 10 rows = 20480B -> 8 blocks/CU (32 waves)

__device__ __forceinline__ void dma16(const float* g, float* l) {
    // async global->LDS DMA, 16B/lane; dest = wave-uniform base + lane*16
    __builtin_amdgcn_global_load_lds(
        (const __attribute__((address_space(1))) unsigned int*)g,
        (__attribute__((address_space(3))) unsigned int*)l,
        16, 0, 0);
}

__device__ __forceinline__ int sgn_bit(float x) {
    return (int)(__float_as_uint(x) >> 31);
}

// phase(x) = 0 for x>=0, pi for x<0 -> adj code a = s(next)-s(cur) in {-1,0,1}
// out[g,t] = (a[g-1,t]==+1 ? in[g-1,t] : 0)
//          + (a[g,t]==0 || (g==0 && a<0) || (g==FF-1 && a>0) ? in[g,t] : 0)
//          + (a[g+1,t]==-1 ? in[g+1,t] : 0)
__global__ __launch_bounds__(THREADS, 8) void sst_kernel(const float* __restrict__ in,
                                                         float* __restrict__ out) {
    __shared__ float sm[ROWS][LROW];

    const int tid    = threadIdx.x;
    const int wid    = tid >> 6;
    const int lane   = tid & 63;
    const int blockT = blockIdx.x * TBLK;
    const int fs     = blockIdx.y * F_CHUNK;
    const int b      = blockIdx.z;

    const float* srcRow = in  + (size_t)b * FF * TT;
    float*       dstRow = out + (size_t)b * FF * TT;

    // ---- stage: 5 DMA instrs per wave. Wave pair (wid>>1) picks the row of the
    // step; (wid&1) picks which 1KB half of the 2KB row this wave covers. ----
    #pragma unroll
    for (int s = 0; s < ROWS / 2; ++s) {
        const int row  = s * 2 + (wid >> 1);
        const int half = wid & 1;
        int f = fs - 1 + row;
        f = f < 0 ? 0 : (f > FF - 1 ? FF - 1 : f);   // halo clamped; pk sentinel neutralizes
        dma16(srcRow + (size_t)f * TT + blockT + half * 256 + lane * 4,
              &sm[row][half * 256]);
    }

    // ---- single full drain (R7: staged counted waits are neutral) ----
    asm volatile("s_waitcnt vmcnt(0)" ::: "memory");
    __builtin_amdgcn_s_barrier();
    __builtin_amdgcn_sched_barrier(0);

    // ---- compute: each thread owns 2 floats of each row ----
    const int  tid2    = tid * 2;
    const int  eidx    = (tid2 + 2 > LROW - 1) ? (LROW - 1) : (tid2 + 2); // tid 255: garbage -> patch
    const bool tailThr = (blockIdx.x == NXBLK - 1) && (tid == THREADS - 1); // t = TT-1: adj 0

    f32x2    v[ROWS];
    unsigned pk[ROWS];

    #pragma unroll
    for (int i = 0; i < ROWS; ++i) {
        v[i] = *reinterpret_cast<const f32x2*>(&sm[i][tid2]);
        const float e = sm[i][eidx];
        const int f   = fs - 1 + i;
        const bool oob = (f < 0) | (f > FF - 1);
        const int s0 = sgn_bit(v[i][0]), s1 = sgn_bit(v[i][1]), s2 = sgn_bit(e);
        const int a0 = s1 - s0 + 1;
        const int a1 = tailThr ? 1 : (s2 - s1 + 1);
        pk[i] = oob ? 0x5u : (unsigned)(a0 | (a1 << 2));
    }

    #pragma unroll
    for (int i = 1; i <= F_CHUNK; ++i) {
        const int g = fs + (i - 1);
        const bool isFirst = (g == 0), isLast = (g == FF - 1);
        const unsigned pp = pk[i - 1], pc = pk[i], pn = pk[i + 1];
        const f32x2    vp = v[i - 1],  vc = v[i],  vn = v[i + 1];
        f32x2 r;
        #pragma unroll
        for (int q = 0; q < 2; ++q) {
            const unsigned cp = (pp >> (2 * q)) & 3u;
            const unsigned cc = (pc >> (2 * q)) & 3u;
            const unsigned cn = (pn >> (2 * q)) & 3u;
            const bool bc = (cc == 1u) || (isFirst && cc == 0u) || (isLast && cc == 2u);
            r[q] = ((cp == 2u) ? vp[q] : 0.f) + (bc ? vc[q] : 0.f) + ((cn == 0u) ? vn[q] : 0.f);
        }
        __builtin_nontemporal_store(
            r, reinterpret_cast<f32x2*>(dstRow + (size_t)g * TT + blockT + tid2));
    }

    // ---- patch epilogue: fix the tile-boundary column (thread 255's second lane
    // used a garbage next-sign). 8 rows, 8 threads; skip the last t-block. ----
    if (blockIdx.x != NXBLK - 1) {
        asm volatile("s_waitcnt vmcnt(0)" ::: "memory");  // this block's stores retired
        __builtin_amdgcn_s_barrier();
        __builtin_amdgcn_sched_barrier(0);
        if (tid < F_CHUNK) {
            const int g = fs + tid;
            const size_t cg = (size_t)(blockT + TBLK - 1);     // global col of last elem
            // values at column cg straight from LDS (rows tid, tid+1, tid+2)
            const float vpv = sm[tid][LROW - 1];
            const float vcv = sm[tid + 1][LROW - 1];
            const float vnv = sm[tid + 2][LROW - 1];
            // next-column signs from global (col cg+1 = next tile's first element)
            const float* nc = srcRow + cg + 1;
            const int am = (g - 1 >= 0)
                         ? (sgn_bit(nc[(size_t)(g - 1) * TT]) - sgn_bit(vpv)) : 9;
            const int ac =  sgn_bit(nc[(size_t)g * TT]) - sgn_bit(vcv);
            const int an = (g + 1 <= FF - 1)
                         ? (sgn_bit(nc[(size_t)(g + 1) * TT]) - sgn_bit(vnv)) : 9;
            const bool bcb = (ac == 0) || (g == 0 && ac < 0) || (g == FF - 1 && ac > 0);
            float r = 0.f;
            if (am == 1)  r += vpv;
            if (bcb)      r += vcv;
            if (an == -1) r += vnv;
            dstRow[(size_t)g * TT + cg] = r;
        }
    }
}

extern "C" void kernel_launch(void* const* d_in, const int* in_sizes, int n_in,
                              void* d_out, int out_size, void* d_ws, size_t ws_size,
                              hipStream_t stream) {
    const float* in  = (const float*)d_in[0];
    float*       out = (float*)d_out;
    // grid: (t-blocks, f-chunks, batch) = (16, 32, 16) -> 8192 one-shot blocks, 8/CU
    dim3 grid(NXBLK, FF / F_CHUNK, BB);
    sst_kernel<<<grid, THREADS, 0, stream>>>(in, out);
}